// Round 9
// baseline (62.918 us; speedup 1.0000x reference)
//
#include <hip/hip_runtime.h>

typedef __attribute__((ext_vector_type(8))) short short8;
typedef __attribute__((ext_vector_type(4))) float f32x4;

#define B_TOTAL 20000
#define B_PAD   20096   // 314 * 64 = 5024 * 4
#define NF      256
#define K2      512
#define NS      10

__device__ __forceinline__ unsigned short f2bf(float x) {
    unsigned u = __builtin_bit_cast(unsigned, x);
    u += 0x7FFFu + ((u >> 16) & 1u);   // round-to-nearest-even
    return (unsigned short)(u >> 16);
}

// K1 (R1-proven, bit-identical): one wave per b-row; 11 independent 1KB row
// loads in flight; coalesced bf16 row write. Blocks 0..127 also convert W.
__global__ __launch_bounds__(256) void gather_combine(
    const float* __restrict__ ue, const int* __restrict__ nidx,
    const int* __restrict__ nodes, const float* __restrict__ w,
    unsigned short* __restrict__ comb, unsigned short* __restrict__ wbf)
{
    const int t = threadIdx.x, blk = blockIdx.x;
    if (blk < 128) {                       // 128 * 256 * 4 = 256*512 W elems
        const int base = blk * 1024 + t * 4;
        const float4 v = *(const float4*)(w + base);
        ushort4 o;
        o.x = f2bf(v.x); o.y = f2bf(v.y); o.z = f2bf(v.z); o.w = f2bf(v.w);
        *(ushort4*)(wbf + base) = o;
    }
    const int lane = t & 63;
    const int b = blk * 4 + (t >> 6);      // one wave per b-row
    if (b >= B_PAD) return;
    unsigned short* crow = comb + (size_t)b * K2;
    if (b < B_TOTAL) {
        const int node = nodes[b];
        const float4 sf = ((const float4*)(ue + (size_t)node * NF))[lane];
        int myidx = 0;
        if (lane < NS) myidx = nidx[b * NS + lane];
        float ax = 0.f, ay = 0.f, az = 0.f, aw = 0.f;
        #pragma unroll
        for (int s = 0; s < NS; ++s) {
            const int is = __shfl(myidx, s);
            const float4 v = ((const float4*)(ue + (size_t)is * NF))[lane];
            ax += v.x; ay += v.y; az += v.z; aw += v.w;
        }
        const float inv = 1.0f / 11.0f;    // reference divides by S+1
        ushort4 s4, n4;
        s4.x = f2bf(sf.x); s4.y = f2bf(sf.y); s4.z = f2bf(sf.z); s4.w = f2bf(sf.w);
        n4.x = f2bf(ax * inv); n4.y = f2bf(ay * inv);
        n4.z = f2bf(az * inv); n4.w = f2bf(aw * inv);
        *(ushort4*)(crow + lane * 4) = s4;
        *(ushort4*)(crow + NF + lane * 4) = n4;
    } else {                               // zero pad rows (ws is poisoned)
        ushort4 z; z.x = z.y = z.z = z.w = 0;
        *(ushort4*)(crow + lane * 4) = z;
        *(ushort4*)(crow + NF + lane * 4) = z;
    }
}

// K2: out[e][b] = relu(sum_k W[e][k]*comb[b][k]).
// Tile 64(b) x 128(e), BK=64, 8 iters, grid (314,2)=628 blocks, 48KB LDS
// (3 blocks/CU). T4 counted-vmcnt pipeline: STAGE(next) -> vmcnt(6) ->
// s_barrier -> ds_read+MFMA -> s_barrier. vmcnt never drains to 0 in-loop.
// LDS layouts: A [kg8][row128][8], B [kg8][row64][8] -> conflict-free b128.
__global__ __launch_bounds__(256) void gemm_relu(
    const unsigned short* __restrict__ wbf,   // [256][512] bf16
    const unsigned short* __restrict__ comb,  // [B_PAD][512] bf16
    float* __restrict__ out)                  // [256][20000] f32
{
    __shared__ unsigned short Alds[2][8192];  // 2 x 16 KB
    __shared__ unsigned short Blds[2][4096];  // 2 x 8 KB
    const int t    = threadIdx.x;
    const int lane = t & 63;
    const int wv   = t >> 6;                  // wave owns e-rows [wv*32, wv*32+32)
    const int n0   = blockIdx.x * 64;         // b-tile
    const int m0   = blockIdx.y * 128;        // e-tile
    const int fr   = lane & 15;
    const int kq   = lane >> 4;

    // STAGE(buf, ks): 6 global_load_lds issues (A:4, B:2), 16B each.
#define STAGE(buf, ks)                                                           \
    do {                                                                         \
        _Pragma("unroll")                                                        \
        for (int L = 0; L < 4; ++L) {                                            \
            const int d = L * 256 + t;                                           \
            const unsigned short* src =                                          \
                wbf + (size_t)(m0 + (d & 127)) * K2 + (ks) * 64 + (d >> 7) * 8;  \
            __builtin_amdgcn_global_load_lds(                                    \
                (const __attribute__((address_space(1))) void*)src,              \
                (__attribute__((address_space(3))) void*)(&Alds[buf][0] + d * 8),\
                16, 0, 0);                                                       \
        }                                                                        \
        _Pragma("unroll")                                                        \
        for (int L = 0; L < 2; ++L) {                                            \
            const int d = L * 256 + t;                                           \
            const unsigned short* src =                                          \
                comb + (size_t)(n0 + (d & 63)) * K2 + (ks) * 64 + (d >> 6) * 8;  \
            __builtin_amdgcn_global_load_lds(                                    \
                (const __attribute__((address_space(1))) void*)src,              \
                (__attribute__((address_space(3))) void*)(&Blds[buf][0] + d * 8),\
                16, 0, 0);                                                       \
        }                                                                        \
    } while (0)

#define COMPUTE(buf)                                                             \
    do {                                                                         \
        const short8* A8 = (const short8*)Alds[buf];                             \
        const short8* B8 = (const short8*)Blds[buf];                             \
        _Pragma("unroll")                                                        \
        for (int h = 0; h < 2; ++h) {                                            \
            short8 af[2], bg[4];                                                 \
            _Pragma("unroll")                                                    \
            for (int i = 0; i < 2; ++i)                                          \
                af[i] = A8[(h * 4 + kq) * 128 + wv * 32 + i * 16 + fr];          \
            _Pragma("unroll")                                                    \
            for (int j = 0; j < 4; ++j)                                          \
                bg[j] = B8[(h * 4 + kq) * 64 + j * 16 + fr];                     \
            _Pragma("unroll")                                                    \
            for (int i = 0; i < 2; ++i)                                          \
                _Pragma("unroll")                                                \
                for (int j = 0; j < 4; ++j)                                      \
                    acc[i][j] = __builtin_amdgcn_mfma_f32_16x16x32_bf16(         \
                        af[i], bg[j], acc[i][j], 0, 0, 0);                       \
        }                                                                        \
    } while (0)

    f32x4 acc[2][4] = {};

    STAGE(0, 0);
    #pragma unroll
    for (int it = 0; it < 8; ++it) {        // fully unrolled -> it&1 compile-time
        const int c = it & 1;
        if (it < 7) {
            if (c == 0) STAGE(1, it + 1); else STAGE(0, it + 1);
            asm volatile("s_waitcnt vmcnt(6)" ::: "memory");   // prev 6 landed
        } else {
            asm volatile("s_waitcnt vmcnt(0)" ::: "memory");   // last tile
        }
        __builtin_amdgcn_s_barrier();
        __builtin_amdgcn_sched_barrier(0);
        if (c == 0) COMPUTE(0); else COMPUTE(1);
        __builtin_amdgcn_sched_barrier(0);
        __builtin_amdgcn_s_barrier();       // all waves done reading buf c
    }
#undef STAGE
#undef COMPUTE

    // ---- epilogue: relu + store ----
    #pragma unroll
    for (int i = 0; i < 2; ++i) {
        const int e = m0 + wv * 32 + i * 16 + kq * 4;
        #pragma unroll
        for (int j = 0; j < 4; ++j) {
            const int b = n0 + j * 16 + fr;
            if (b < B_TOTAL) {
                #pragma unroll
                for (int r = 0; r < 4; ++r)
                    out[(size_t)(e + r) * B_TOTAL + b] = fmaxf(acc[i][j][r], 0.0f);
            }
        }
    }
}

extern "C" void kernel_launch(void* const* d_in, const int* in_sizes, int n_in,
                              void* d_out, int out_size, void* d_ws, size_t ws_size,
                              hipStream_t stream) {
    const float* ue    = (const float*)d_in[0];
    // d_in[1] = features_ap: unused (ue2ue mode)
    const int*   nidx  = (const int*)d_in[2];
    const int*   nodes = (const int*)d_in[3];
    const float* w     = (const float*)d_in[4];
    float*       out   = (float*)d_out;

    unsigned short* comb = (unsigned short*)d_ws;              // [B_PAD][512] bf16 = 20.58 MB
    unsigned short* wbf  = comb + (size_t)B_PAD * K2;          // [256][512] bf16  = 0.26 MB

    hipLaunchKernelGGL(gather_combine, dim3(B_PAD / 4), dim3(256), 0, stream,
                       ue, nidx, nodes, w, comb, wbf);
    hipLaunchKernelGGL(gemm_relu, dim3(B_PAD / 64, 2), dim3(256), 0, stream,
                       wbf, comb, out);
}